// Round 2
// baseline (234.290 us; speedup 1.0000x reference)
//
#include <hip/hip_runtime.h>

typedef short short8 __attribute__((ext_vector_type(8)));
typedef float float4v __attribute__((ext_vector_type(4)));
typedef int int4v __attribute__((ext_vector_type(4)));
typedef unsigned int uint2v __attribute__((ext_vector_type(2)));
typedef unsigned short ushort_t;

#define INV_EXT (1.0f / 0.048f)
#define HN 32
#define KK 15
#define CIN 64
#define COUT 64
#define PB 16      /* points per block */
#define JH 512     /* j-slots per ct-half (2 of 4 ct groups) */
#define NSLOT 16   /* stats atomic slots */

// round-half-up bf16
__device__ inline ushort_t rh_bf16(float f) {
    return (ushort_t)((__float_as_uint(f) + 0x8000u) >> 16);
}
// pack two floats into two bf16 in one u32 (lo = a, hi = b)
__device__ inline unsigned pk_bf16(float a, float b) {
    unsigned ua = __float_as_uint(a) + 0x8000u;
    unsigned ub = __float_as_uint(b) + 0x8000u;
    return (ua >> 16) | (ub & 0xffff0000u);
}

union Frag8 { short8 s; unsigned u[4]; };

// wtS element index within half-tile: row p (1 KB = 512 shorts), local j (0..511).
// 16B-granule XOR swizzle by p so phase-3 reads (p = lane&15) spread banks.
__device__ inline int wtJh(int p, int j) {
    return p * JH + ((((j >> 3) ^ (p & 7)) << 3) | (j & 7));
}

// ================= K1: main KPConv (ct-split, single-fetch, 6 blocks/CU) ======
// LDS: wtS 16 KB + indS 2 KB = 18 KB. Occupancy is VGPR-capped (~6 blocks/CU):
// each xb row is fetched ONCE as interleaved dword-pairs; the half-1 dwords
// (32 VGPRs) stay live across phase 3a and feed phase 2b with zero loads.
// (Round-1 lesson: re-gathering half-1 separately missed L2 — lines churn in
// ~10 us between the two phases — costing +138 MB FETCH and the whole win.)
template <bool XB>
__global__ __launch_bounds__(256, 6)
void kpconv_main(const float* __restrict__ q_pts,
                 const float* __restrict__ s_pts,
                 const int*   __restrict__ inds,
                 const float* __restrict__ x,
                 const float* __restrict__ kpts,
                 const ushort_t* __restrict__ W3,   // [128 kd-octets][64 d][8] bf16
                 const unsigned* __restrict__ xb,   // [N][16 tt][2: hf0,hf1 dwords]
                 float* __restrict__ out,
                 float* __restrict__ sums, int N)
{
    __shared__ __align__(16) short wtS[PB * JH];   // 16 KB
    __shared__ int indS[PB * HN];                  // 2 KB

    const int t = threadIdx.x;
    const int n0 = blockIdx.x * PB;
    const int lane = t & 63;
    const int wid = t >> 6;
    const int l15 = lane & 15;
    const int q = lane >> 4;

    float* fp = (float*)wtS;   // coord region: fp[p*256 + c*32 + h], 384 B of 1 KB row

    // ---- phase 0: gather RAW neighbor coords + indices (q subtracted in ph1) ----
    for (int it = 0; it < 2; ++it) {
        int pi = t + it * 256;          // (p,h)
        int p = pi >> 5, h = pi & 31;
        int n = n0 + p;
        float sx = 1e9f, sy = 1e9f, sz = 1e9f; int idx = 0;
        if (n < N) {
            idx = inds[n * HN + h];
            const float* sp = s_pts + (size_t)idx * 3;
            sx = sp[0]; sy = sp[1]; sz = sp[2];
        }
        indS[pi] = idx;
        fp[p * 256 + h]      = sx;
        fp[p * 256 + 32 + h] = sy;
        fp[p * 256 + 64 + h] = sz;
    }
    __syncthreads();

    // ---- phase 1: influence weights into A-fragments (A[m=k'=l15][k=h=q*8+j]) ----
    int kidx = l15 < KK ? l15 : 0;
    float kx = kpts[kidx * 3 + 0];
    float ky = kpts[kidx * 3 + 1];
    float kz = kpts[kidx * 3 + 2];
    if (l15 >= KK) { kx = 3e4f; ky = 3e4f; kz = 3e4f; }  // pad kp -> w = 0
    Frag8 afrag[4];
#pragma unroll
    for (int i = 0; i < 4; ++i) {
        int p = wid * 4 + i;
        int n = n0 + p;
        int nc = n < N ? n : 0;
        float qkx = q_pts[nc * 3 + 0] + kx;   // s - (q+kp): err ~6e-8 << d
        float qky = q_pts[nc * 3 + 1] + ky;
        float qkz = q_pts[nc * 3 + 2] + kz;
        int base = p * 256 + q * 8;
        float4v x0 = *(float4v*)&fp[base],      x1 = *(float4v*)&fp[base + 4];
        float4v y0 = *(float4v*)&fp[base + 32], y1 = *(float4v*)&fp[base + 36];
        float4v z0 = *(float4v*)&fp[base + 64], z1 = *(float4v*)&fp[base + 68];
        float w[8];
#pragma unroll
        for (int j = 0; j < 8; ++j) {
            float dx = (j < 4 ? x0[j & 3] : x1[j & 3]) - qkx;
            float dy = (j < 4 ? y0[j & 3] : y1[j & 3]) - qky;
            float dz = (j < 4 ? z0[j & 3] : z1[j & 3]) - qkz;
            float d = __builtin_amdgcn_sqrtf(fmaf(dx, dx, fmaf(dy, dy, dz * dz)));
            w[j] = fmaxf(fmaf(d, -INV_EXT, 1.0f), 0.0f);
        }
#pragma unroll
        for (int jj = 0; jj < 4; ++jj)
            afrag[i].u[jj] = pk_bf16(w[2 * jj], w[2 * jj + 1]);
    }
    // No barrier: each wave read only its own rows above, writes only its own below.

    const int d0 = wid * 16;
    float4v acc3 = {0.f, 0.f, 0.f, 0.f};
    const ushort_t* wb = W3 + (size_t)q * 512 + (d0 + l15) * 8;

    unsigned D1[4][8];   // half-1 dwords, held across phase 3a (32 VGPRs)

    // ---- phase 2a: wt[k'][c] for ct = 0,1; single fetch of BOTH halves ----
#pragma unroll
    for (int i = 0; i < 4; ++i) {
        int p = wid * 4 + i;
        int ibase = p * HN + q * 8;
        int4v ia = *(int4v*)&indS[ibase];       // broadcast b128
        int4v ib = *(int4v*)&indS[ibase + 4];
        unsigned T0[8];
        if constexpr (XB) {
#pragma unroll
            for (int j = 0; j < 8; ++j) {
                int idx = j < 4 ? ia[j] : ib[j - 4];
                uint2v v = *(const uint2v*)(xb + (size_t)idx * 32 + l15 * 2);
                T0[j] = v[0];
                D1[i][j] = v[1];
            }
        } else {
#pragma unroll
            for (int j = 0; j < 8; ++j) {
                int idx = j < 4 ? ia[j] : ib[j - 4];
                const float* rp = x + (size_t)idx * CIN;
                T0[j]    = pk_bf16(rp[l15], rp[16 + l15]);
                D1[i][j] = pk_bf16(rp[32 + l15], rp[48 + l15]);
            }
        }
#pragma unroll
        for (int ct = 0; ct < 2; ++ct) {
            Frag8 b;
#pragma unroll
            for (int jj = 0; jj < 4; ++jj) {
                unsigned lo = T0[2 * jj], hi = T0[2 * jj + 1];
                b.u[jj] = ct == 0 ? ((lo & 0xffffu) | (hi << 16))
                                  : ((lo >> 16) | (hi & 0xffff0000u));
            }
            float4v acc = {0.f, 0.f, 0.f, 0.f};
            acc = __builtin_amdgcn_mfma_f32_16x16x32_bf16(afrag[i].s, b.s, acc, 0, 0, 0);
            // D row m = k' = q*4+r, col n = c = ct*16+l15.
            // kd-slot j = quad*4 + r, quad = l15 + 16*(q^ct) + 64*ct
            uint2v v2;
            v2[0] = pk_bf16(acc[0], acc[1]);
            v2[1] = pk_bf16(acc[2], acc[3]);
            int quad = l15 + 16 * (q ^ ct) + 64 * ct;
            *(uint2v*)&wtS[wtJh(p, quad * 4)] = v2;
        }
    }
    __syncthreads();

    // ---- phase 3a: OUT += wt-half0 @ W3[octets 0..63] ----
#pragma unroll 8
    for (int s = 0; s < 16; ++s) {
        short8 a = *(short8*)&wtS[wtJh(l15, s * 32 + q * 8)];
        short8 bb = *(const short8*)(wb + (size_t)s * 2048);
        acc3 = __builtin_amdgcn_mfma_f32_16x16x32_bf16(a, bb, acc3, 0, 0, 0);
    }
    __syncthreads();   // all reads done before phase 2b overwrites wtS

    // ---- phase 2b: wt[k'][c] for ct = 2,3 from held registers (no loads) ----
#pragma unroll
    for (int i = 0; i < 4; ++i) {
        int p = wid * 4 + i;
#pragma unroll
        for (int cth = 0; cth < 2; ++cth) {
            int ct = 2 + cth;
            Frag8 b;
#pragma unroll
            for (int jj = 0; jj < 4; ++jj) {
                unsigned lo = D1[i][2 * jj], hi = D1[i][2 * jj + 1];
                b.u[jj] = cth == 0 ? ((lo & 0xffffu) | (hi << 16))
                                   : ((lo >> 16) | (hi & 0xffff0000u));
            }
            float4v acc = {0.f, 0.f, 0.f, 0.f};
            acc = __builtin_amdgcn_mfma_f32_16x16x32_bf16(afrag[i].s, b.s, acc, 0, 0, 0);
            uint2v v2;
            v2[0] = pk_bf16(acc[0], acc[1]);
            v2[1] = pk_bf16(acc[2], acc[3]);
            int quad = l15 + 16 * (q ^ ct) + 64 * ct;
            int jloc = quad * 4 - JH;            // [0, 512)
            *(uint2v*)&wtS[wtJh(p, jloc)] = v2;
        }
    }
    __syncthreads();

    // ---- phase 3b: OUT += wt-half1 @ W3[octets 64..127] ----
    {
        const ushort_t* wbh = wb + (size_t)64 * 512;
#pragma unroll 8
        for (int s = 0; s < 16; ++s) {
            short8 a = *(short8*)&wtS[wtJh(l15, s * 32 + q * 8)];
            short8 bb = *(const short8*)(wbh + (size_t)s * 2048);
            acc3 = __builtin_amdgcn_mfma_f32_16x16x32_bf16(a, bb, acc3, 0, 0, 0);
        }
    }

    // ---- epilogue: store + fused per-channel stats (slotted atomics) ----
    {
        float s1 = 0.f, s2 = 0.f;
#pragma unroll
        for (int r = 0; r < 4; ++r) {
            int p = q * 4 + r;
            int n = n0 + p;
            float v = acc3[r];
            if (n < N) { out[n * COUT + d0 + l15] = v; s1 += v; s2 += v * v; }
        }
        s1 += __shfl_xor(s1, 16); s2 += __shfl_xor(s2, 16);
        s1 += __shfl_xor(s1, 32); s2 += __shfl_xor(s2, 32);
        if (q == 0) {
            int slot = blockIdx.x & (NSLOT - 1);
            atomicAdd(&sums[slot * 128 + d0 + l15], s1);
            atomicAdd(&sums[slot * 128 + 64 + d0 + l15], s2);
        }
    }
}

// ================= K0: prep (zero stats, W->W3 blocked layout, x->xb pairs) ===
template <bool XB>
__global__ void prep_kernel(const float* __restrict__ W, const float* __restrict__ x,
                            float* sums, ushort_t* W3, unsigned* xb, int N)
{
    long gt = (long)blockIdx.x * 256 + threadIdx.x;
    long stride = (long)gridDim.x * 256;
    if (gt < NSLOT * 128) sums[gt] = 0.f;
    for (long i = gt; i < COUT * 1024; i += stride) {
        int d = (int)((i >> 3) & 63);
        int j = (int)(((i >> 9) << 3) | (i & 7));  // kd-slot
        int quad = j >> 2, r = j & 3;
        int l15 = quad & 15, e = (quad >> 4) & 3, ct = quad >> 6;
        int k = (e ^ ct) * 4 + r, c = ct * 16 + l15;
        W3[i] = (k < KK) ? rh_bf16(W[(k * CIN + c) * COUT + d]) : (ushort_t)0;
    }
    if constexpr (XB) {
        // interleaved pairs: xb[n][tt*2]   = pk(bf16 x[c=tt],    bf16 x[c=16+tt])
        //                    xb[n][tt*2+1] = pk(bf16 x[c=32+tt], bf16 x[c=48+tt])
        // -> lane tt dwordx2 load returns (half0, half1) for its channel slot.
        long nq = (long)N * 16;
        for (long iq = gt; iq < nq; iq += stride) {
            long n = iq >> 4; int tt = (int)(iq & 15);
            const float* xp = x + n * 64;
            uint2v v;
            v[0] = pk_bf16(xp[tt],      xp[tt + 16]);
            v[1] = pk_bf16(xp[tt + 32], xp[tt + 48]);
            *(uint2v*)(xb + n * 32 + tt * 2) = v;
        }
    }
}

// ================= K2: reduce slots + instance-norm + LeakyReLU ========
__global__ void norm_kernel(float* out, const float* __restrict__ sums, int N)
{
    __shared__ float meanS[64], invS[64];
    int t = threadIdx.x;
    if (t < 64) {
        float s1 = 0.f, s2 = 0.f;
#pragma unroll
        for (int sl = 0; sl < NSLOT; ++sl) {
            s1 += sums[sl * 128 + t];
            s2 += sums[sl * 128 + 64 + t];
        }
        float invN = 1.0f / (float)N;
        float mean = s1 * invN;
        float var = fmaxf(s2 * invN - mean * mean, 0.f);
        meanS[t] = mean;
        invS[t] = rsqrtf(var + 1e-5f);
    }
    __syncthreads();
    long total = (long)N * 64 / 4;
    for (long i = (long)blockIdx.x * blockDim.x + t; i < total;
         i += (long)gridDim.x * blockDim.x) {
        int cb = (int)((i * 4) & 63);
        float4v v = *(float4v*)&out[i * 4];
#pragma unroll
        for (int j = 0; j < 4; ++j) {
            float val = (v[j] - meanS[cb + j]) * invS[cb + j];
            v[j] = val >= 0.f ? val : 0.1f * val;
        }
        *(float4v*)&out[i * 4] = v;
    }
}

extern "C" void kernel_launch(void* const* d_in, const int* in_sizes, int n_in,
                              void* d_out, int out_size, void* d_ws, size_t ws_size,
                              hipStream_t stream)
{
    const float* q  = (const float*)d_in[0];
    const float* s  = (const float*)d_in[1];
    const int* inds = (const int*)d_in[2];
    const float* x  = (const float*)d_in[3];
    const float* kp = (const float*)d_in[4];
    const float* W  = (const float*)d_in[5];
    float* out = (float*)d_out;
    int N = in_sizes[0] / 3;

    float* sums  = (float*)d_ws;                                // 8 KB
    ushort_t* W3 = (ushort_t*)((char*)d_ws + 8192);             // 128 KB
    unsigned* xb = (unsigned*)((char*)d_ws + 8192 + 131072);    // N*128 B
    bool useXB = ws_size >= 8192 + 131072 + (size_t)N * CIN * 2;

    int nblk = (N + PB - 1) / PB;
    if (useXB) {
        prep_kernel<true ><<<1024, 256, 0, stream>>>(W, x, sums, W3, xb, N);
        kpconv_main<true ><<<nblk, 256, 0, stream>>>(q, s, inds, x, kp, W3, xb, out, sums, N);
    } else {
        prep_kernel<false><<<1024, 256, 0, stream>>>(W, x, sums, W3, xb, N);
        kpconv_main<false><<<nblk, 256, 0, stream>>>(q, s, inds, x, kp, W3, xb, out, sums, N);
    }
    norm_kernel<<<2048, 256, 0, stream>>>(out, sums, N);
}

// Round 3
// 126.698 us; speedup vs baseline: 1.8492x; 1.8492x over previous
//
#include <hip/hip_runtime.h>

typedef short short8 __attribute__((ext_vector_type(8)));
typedef float float4v __attribute__((ext_vector_type(4)));
typedef int int4v __attribute__((ext_vector_type(4)));
typedef unsigned int uint2v __attribute__((ext_vector_type(2)));
typedef unsigned int uint4v __attribute__((ext_vector_type(4)));
typedef unsigned short ushort_t;

#define INV_EXT (1.0f / 0.048f)
#define EXT2 (0.048f * 0.048f)
#define HN 32
#define KK 15
#define CIN 64
#define COUT 64
#define PB 16      /* points per block */
#define KDIM 1024  /* padded 16 k' * 64 c, order defined by j-map */
#define NSLOT 16   /* stats atomic slots */

// round-half-up bf16
__device__ inline ushort_t rh_bf16(float f) {
    return (ushort_t)((__float_as_uint(f) + 0x8000u) >> 16);
}
// pack two floats into two bf16 in one u32 (lo = a, hi = b)
__device__ inline unsigned pk_bf16(float a, float b) {
    unsigned ua = __float_as_uint(a) + 0x8000u;
    unsigned ub = __float_as_uint(b) + 0x8000u;
    return (ua >> 16) | (ub & 0xffff0000u);
}

union Frag8 { short8 s; unsigned u[4]; };

// wtS element index: row p (1024 shorts), logical kd-slot j. 16B-granule XOR
// swizzle by p so phase-3 reads (p = lane&15) spread across banks. (R0-proven.)
__device__ inline int wtJ(int p, int j) {
    return p * KDIM + ((((j >> 3) ^ (p & 7)) << 3) | (j & 7));
}

// ================= K1: main KPConv with exact-zero sparsity skip ==============
// Data insight: neighbors are uniformly random points at distance ~1.4 vs kernel
// extent 0.048 -> ~99.8% of (query,neighbor) pairs have influence EXACTLY 0.0.
// Skipping them is algebraically exact (contribution is 0 * feature). ~96% of
// 16-point blocks have no active point at all -> skip gather/MFMA/out entirely.
// Active path reuses the round-0-verified fragment maps unchanged.
__global__ __launch_bounds__(256, 4)
void kpconv_main(const float* __restrict__ q_pts,
                 const float* __restrict__ s_pts,
                 const int*   __restrict__ inds,
                 const float* __restrict__ x,
                 const float* __restrict__ kpts,
                 const ushort_t* __restrict__ W3,   // [128 kd-octets][64 d][8] bf16
                 float* __restrict__ out,
                 float* __restrict__ sums,
                 unsigned* __restrict__ mask, int N)
{
    __shared__ __align__(16) short wtS[PB * KDIM];  // 32 KB; rows double as coord scratch
    __shared__ int indS[PB * HN];                   // 2 KB
    __shared__ int bact;

    const int t = threadIdx.x;
    const int n0 = blockIdx.x * PB;
    const int lane = t & 63;
    const int wid = t >> 6;
    const int l15 = lane & 15;
    const int q = lane >> 4;
    if (t == 0) bact = 0;

    float* fp = (float*)wtS;   // coords: fp[p*512 + c*32 + h] (384 B of 2 KB row)

    // ---- phase 0: gather RAW neighbor coords + indices ----
    for (int it = 0; it < 2; ++it) {
        int pi = t + it * 256;          // (p,h)
        int p = pi >> 5, h = pi & 31;
        int n = n0 + p;
        float sx = 1e9f, sy = 1e9f, sz = 1e9f; int idx = 0;
        if (n < N) {
            idx = inds[n * HN + h];
            const float* sp = s_pts + (size_t)idx * 3;
            sx = sp[0]; sy = sp[1]; sz = sp[2];
        }
        indS[pi] = idx;
        fp[p * 512 + h]      = sx;
        fp[p * 512 + 32 + h] = sy;
        fp[p * 512 + 64 + h] = sz;
    }
    __syncthreads();

    // ---- phase 1: cheap sq-test; sqrt + A-fragment only for active points ----
    int kidx = l15 < KK ? l15 : 0;
    float kx = kpts[kidx * 3 + 0];
    float ky = kpts[kidx * 3 + 1];
    float kz = kpts[kidx * 3 + 2];
    if (l15 >= KK) { kx = 3e4f; ky = 3e4f; kz = 3e4f; }  // pad kp -> inactive
    Frag8 afrag[4];
    int pbits = 0;
#pragma unroll
    for (int i = 0; i < 4; ++i) {
        int p = wid * 4 + i;
        int n = n0 + p;
        int nc = n < N ? n : 0;
        float qkx = q_pts[nc * 3 + 0] + kx;   // s - (q+kp): err ~6e-8 << d
        float qky = q_pts[nc * 3 + 1] + ky;
        float qkz = q_pts[nc * 3 + 2] + kz;
        int base = p * 512 + q * 8;
        float4v x0 = *(float4v*)&fp[base],      x1 = *(float4v*)&fp[base + 4];
        float4v y0 = *(float4v*)&fp[base + 32], y1 = *(float4v*)&fp[base + 36];
        float4v z0 = *(float4v*)&fp[base + 64], z1 = *(float4v*)&fp[base + 68];
        float sq[8];
        bool actL = false;
#pragma unroll
        for (int j = 0; j < 8; ++j) {
            float dx = (j < 4 ? x0[j & 3] : x1[j & 3]) - qkx;
            float dy = (j < 4 ? y0[j & 3] : y1[j & 3]) - qky;
            float dz = (j < 4 ? z0[j & 3] : z1[j & 3]) - qkz;
            sq[j] = fmaf(dx, dx, fmaf(dy, dy, dz * dz));
            actL |= (sq[j] < EXT2);
        }
        if (__ballot(actL)) {               // wave-uniform
            pbits |= 1 << i;
            float w[8];
#pragma unroll
            for (int j = 0; j < 8; ++j) {
                float d = __builtin_amdgcn_sqrtf(sq[j]);
                w[j] = fmaxf(fmaf(d, -INV_EXT, 1.0f), 0.0f);
            }
#pragma unroll
            for (int jj = 0; jj < 4; ++jj)
                afrag[i].u[jj] = pk_bf16(w[2 * jj], w[2 * jj + 1]);
        }
    }
    if (lane == 0 && pbits) atomicOr(&bact, pbits << (wid * 4));
    __syncthreads();
    const int ba = bact;
    if (t == 0) mask[blockIdx.x] = (unsigned)ba;
    if (ba == 0) return;    // ~96% of blocks: done. norm writes their rows.

    // ---- phase 2: active points -> gather x + MFMA; inactive -> zero wtS row ----
#pragma unroll
    for (int i = 0; i < 4; ++i) {
        int p = wid * 4 + i;
        if (pbits & (1 << i)) {
            int ibase = p * HN + q * 8;
            int4v ia = *(int4v*)&indS[ibase];       // broadcast b128
            int4v ib = *(int4v*)&indS[ibase + 4];
            const float* rpf[8];
#pragma unroll
            for (int j = 0; j < 8; ++j) {
                int idx = j < 4 ? ia[j] : ib[j - 4];
                rpf[j] = x + (size_t)idx * CIN;
            }
#pragma unroll
            for (int ct = 0; ct < 4; ++ct) {
                short8 b;
#pragma unroll
                for (int j = 0; j < 8; ++j)
                    b[j] = (short)rh_bf16(rpf[j][ct * 16 + l15]);
                float4v acc = {0.f, 0.f, 0.f, 0.f};
                acc = __builtin_amdgcn_mfma_f32_16x16x32_bf16(afrag[i].s, b, acc, 0, 0, 0);
                // D row m = k' = q*4+r, col n = c = ct*16+l15.
                // kd-slot j = quad*4 + r, quad = l15 + 16*(q^ct) + 64*ct
                uint2v v2;
                v2[0] = pk_bf16(acc[0], acc[1]);
                v2[1] = pk_bf16(acc[2], acc[3]);
                int quad = l15 + 16 * (q ^ ct) + 64 * ct;
                *(uint2v*)&wtS[wtJ(p, quad * 4)] = v2;
            }
        } else {
            // zero the 2 KB row: 64 lanes x 32 B (swizzle-agnostic: zeros)
            uint4v z = {0u, 0u, 0u, 0u};
            *(uint4v*)&wtS[p * KDIM + lane * 16]     = z;
            *(uint4v*)&wtS[p * KDIM + lane * 16 + 8] = z;
        }
    }
    __syncthreads();

    // ---- phase 3: OUT[16p x 64d] = wt[16p x 1024j] @ W3[1024j x 64d] ----
    const int d0 = wid * 16;
    float4v acc3 = {0.f, 0.f, 0.f, 0.f};
    const ushort_t* wb = W3 + (size_t)q * 512 + (d0 + l15) * 8;
#pragma unroll 8
    for (int s = 0; s < 32; ++s) {
        short8 a = *(short8*)&wtS[wtJ(l15, s * 32 + q * 8)];
        short8 bb = *(const short8*)(wb + (size_t)s * 2048);
        acc3 = __builtin_amdgcn_mfma_f32_16x16x32_bf16(a, bb, acc3, 0, 0, 0);
    }

    // ---- epilogue: store + stats for ACTIVE rows only ----
    {
        float s1 = 0.f, s2 = 0.f;
#pragma unroll
        for (int r = 0; r < 4; ++r) {
            int p = q * 4 + r;
            int n = n0 + p;
            float v = acc3[r];
            if (((ba >> p) & 1) && n < N) {
                out[n * COUT + d0 + l15] = v;
                s1 += v; s2 += v * v;
            }
        }
        s1 += __shfl_xor(s1, 16); s2 += __shfl_xor(s2, 16);
        s1 += __shfl_xor(s1, 32); s2 += __shfl_xor(s2, 32);
        if (q == 0) {
            int slot = blockIdx.x & (NSLOT - 1);
            atomicAdd(&sums[slot * 128 + d0 + l15], s1);
            atomicAdd(&sums[slot * 128 + 64 + d0 + l15], s2);
        }
    }
}

// ================= K0: prep (zero stats, W->W3 blocked layout) ================
__global__ void prep_kernel(const float* __restrict__ W, float* sums, ushort_t* W3)
{
    int gt = blockIdx.x * 256 + threadIdx.x;
    int stride = gridDim.x * 256;
    if (gt < NSLOT * 128) sums[gt] = 0.f;
    for (int i = gt; i < COUT * KDIM; i += stride) {
        int d = (i >> 3) & 63;
        int j = ((i >> 9) << 3) | (i & 7);  // kd-slot
        int quad = j >> 2, r = j & 3;
        int l15 = quad & 15, e = (quad >> 4) & 3, ct = quad >> 6;
        int k = (e ^ ct) * 4 + r, c = ct * 16 + l15;
        W3[i] = (k < KK) ? rh_bf16(W[(k * CIN + c) * COUT + d]) : (ushort_t)0;
    }
}

// ====== K2: reduce slots + instance-norm + LeakyReLU (mask-aware) =============
// Inactive rows (pre-norm value exactly 0, never written by main) get the
// per-channel constant leaky((0-mean)*inv) with NO read of out.
__global__ void norm_kernel(float* __restrict__ out, const float* __restrict__ sums,
                            const unsigned* __restrict__ mask, int N)
{
    __shared__ float meanS[64], invS[64], czS[64];
    int t = threadIdx.x;
    if (t < 64) {
        float s1 = 0.f, s2 = 0.f;
#pragma unroll
        for (int sl = 0; sl < NSLOT; ++sl) {
            s1 += sums[sl * 128 + t];
            s2 += sums[sl * 128 + 64 + t];
        }
        float invN = 1.0f / (float)N;
        float mean = s1 * invN;
        float var = fmaxf(s2 * invN - mean * mean, 0.f);
        float inv = rsqrtf(var + 1e-5f);
        meanS[t] = mean;
        invS[t] = inv;
        float cz = (0.f - mean) * inv;
        czS[t] = cz >= 0.f ? cz : 0.1f * cz;
    }
    __syncthreads();
    long total = (long)N * 16;   // float4 chunks
    for (long i = (long)blockIdx.x * blockDim.x + t; i < total;
         i += (long)gridDim.x * blockDim.x) {
        int cb = (int)((i * 4) & 63);
        long n = i >> 4;
        unsigned mw = mask[n >> 4];
        float4v v;
        if ((mw >> ((int)n & 15)) & 1) {
            v = *(float4v*)&out[i * 4];
#pragma unroll
            for (int j = 0; j < 4; ++j) {
                float val = (v[j] - meanS[cb + j]) * invS[cb + j];
                v[j] = val >= 0.f ? val : 0.1f * val;
            }
        } else {
#pragma unroll
            for (int j = 0; j < 4; ++j) v[j] = czS[cb + j];
        }
        *(float4v*)&out[i * 4] = v;
    }
}

extern "C" void kernel_launch(void* const* d_in, const int* in_sizes, int n_in,
                              void* d_out, int out_size, void* d_ws, size_t ws_size,
                              hipStream_t stream)
{
    const float* q  = (const float*)d_in[0];
    const float* s  = (const float*)d_in[1];
    const int* inds = (const int*)d_in[2];
    const float* x  = (const float*)d_in[3];
    const float* kp = (const float*)d_in[4];
    const float* W  = (const float*)d_in[5];
    float* out = (float*)d_out;
    int N = in_sizes[0] / 3;

    float* sums  = (float*)d_ws;                                  // 8 KB
    ushort_t* W3 = (ushort_t*)((char*)d_ws + 8192);               // 128 KB
    unsigned* mask = (unsigned*)((char*)d_ws + 8192 + 131072);    // nblk * 4 B

    int nblk = (N + PB - 1) / PB;
    prep_kernel<<<256, 256, 0, stream>>>(W, sums, W3);
    kpconv_main<<<nblk, 256, 0, stream>>>(q, s, inds, x, kp, W3, out, sums, mask, N);
    norm_kernel<<<2048, 256, 0, stream>>>(out, sums, mask, N);
}

// Round 4
// 120.986 us; speedup vs baseline: 1.9365x; 1.0472x over previous
//
#include <hip/hip_runtime.h>

typedef short short8 __attribute__((ext_vector_type(8)));
typedef float float4v __attribute__((ext_vector_type(4)));
typedef int int4v __attribute__((ext_vector_type(4)));
typedef unsigned int uint2v __attribute__((ext_vector_type(2)));
typedef unsigned int uint4v __attribute__((ext_vector_type(4)));
typedef unsigned short ushort_t;

#define INV_EXT (1.0f / 0.048f)
#define EXT 0.048f
#define HN 32
#define KK 15
#define CIN 64
#define COUT 64
#define PB 16      /* points per block */
#define KDIM 1024  /* padded 16 k' * 64 c, order defined by j-map */
#define NSLOT 16   /* stats atomic slots */

// round-half-up bf16
__device__ inline ushort_t rh_bf16(float f) {
    return (ushort_t)((__float_as_uint(f) + 0x8000u) >> 16);
}
// pack two floats into two bf16 in one u32 (lo = a, hi = b)
__device__ inline unsigned pk_bf16(float a, float b) {
    unsigned ua = __float_as_uint(a) + 0x8000u;
    unsigned ub = __float_as_uint(b) + 0x8000u;
    return (ua >> 16) | (ub & 0xffff0000u);
}

union Frag8 { short8 s; unsigned u[4]; };

// wtS element index: row p (1024 shorts), logical kd-slot j. 16B-granule XOR
// swizzle by p so phase-3 reads (p = lane&15) spread across banks. (R0-proven.)
__device__ inline int wtJ(int p, int j) {
    return p * KDIM + ((((j >> 3) ^ (p & 7)) << 3) | (j & 7));
}

// ================= K1: main KPConv, triangle-inequality screen in phase 0 =====
// Sparsity: random neighbors sit at |diff| ~ 1.4 vs reach max|kp|+ext ~ 0.11 ->
// ~99.6% of pairs have ALL 16 influences exactly 0 (triangle inequality:
// |diff| >= max|kp|+ext  =>  |diff-kp| >= ext for every kp). One sq-test per
// (point,neighbor) during phase 0 replaces the 16-kernel-point field; ~94% of
// blocks exit after phase 0. Active path = R0-verified fragment maps unchanged.
__global__ __launch_bounds__(256, 4)
void kpconv_main(const float* __restrict__ q_pts,
                 const float* __restrict__ s_pts,
                 const int*   __restrict__ inds,
                 const float* __restrict__ x,
                 const float* __restrict__ kpts,
                 const ushort_t* __restrict__ W3,   // [128 kd-octets][64 d][8] bf16
                 float* __restrict__ out,
                 float* __restrict__ sums,
                 unsigned* __restrict__ mask, int N)
{
    __shared__ __align__(16) short wtS[PB * KDIM];  // 32 KB; rows double as coord scratch
    __shared__ int indS[PB * HN];                   // 2 KB
    __shared__ unsigned actS[PB];                   // per-point activity (lane ballots)

    const int t = threadIdx.x;
    const int n0 = blockIdx.x * PB;
    const int lane = t & 63;
    const int wid = t >> 6;
    const int l15 = lane & 15;
    const int q = lane >> 4;

    float* fp = (float*)wtS;   // coords: fp[p*512 + c*32 + h] (384 B of 2 KB row)

    // ---- screen bound: (max_k |kp_k| + ext + eps)^2, wave-computed ----
    float bound2;
    {
        int ki = l15 < KK ? l15 : 0;
        float bx = kpts[ki * 3 + 0], by = kpts[ki * 3 + 1], bz = kpts[ki * 3 + 2];
        float kn = l15 < KK ? __builtin_amdgcn_sqrtf(fmaf(bx, bx, fmaf(by, by, bz * bz)))
                            : 0.f;
        kn = fmaxf(kn, __shfl_xor(kn, 1));
        kn = fmaxf(kn, __shfl_xor(kn, 2));
        kn = fmaxf(kn, __shfl_xor(kn, 4));
        kn = fmaxf(kn, __shfl_xor(kn, 8));
        float b = kn + EXT + 1e-4f;      // overestimate-only margin: skip stays exact
        bound2 = b * b;
    }

    // ---- phase 0: gather coords + indices, per-pair screen, per-point ballot ----
    for (int it = 0; it < 2; ++it) {
        int pi = t + it * 256;          // (p,h)
        int p = pi >> 5, h = pi & 31;
        int n = n0 + p;
        float sx = 1e9f, sy = 1e9f, sz = 1e9f; int idx = 0;
        float dd = 1e18f;
        if (n < N) {
            idx = inds[n * HN + h];
            const float* sp = s_pts + (size_t)idx * 3;
            sx = sp[0]; sy = sp[1]; sz = sp[2];
            float ex = sx - q_pts[n * 3 + 0];
            float ey = sy - q_pts[n * 3 + 1];
            float ez = sz - q_pts[n * 3 + 2];
            dd = fmaf(ex, ex, fmaf(ey, ey, ez * ez));
        }
        indS[pi] = idx;
        fp[p * 512 + h]      = sx;
        fp[p * 512 + 32 + h] = sy;
        fp[p * 512 + 64 + h] = sz;
        unsigned long long bal = __ballot(dd < bound2);
        if (lane == 0)  actS[p] = (unsigned)(bal & 0xffffffffull);
        if (lane == 32) actS[p] = (unsigned)(bal >> 32);
    }
    __syncthreads();

    // ---- block/point activity masks (uniform across waves) ----
    unsigned long long bb = __ballot(actS[l15] != 0);
    const unsigned ba = (unsigned)bb & 0xffffu;
    if (t == 0) mask[blockIdx.x] = ba;
    if (ba == 0) return;    // ~94% of blocks: done. norm writes their rows.
    const int pbits = (ba >> (wid * 4)) & 0xf;

    // ---- phase 1: A-fragments for this wave's ACTIVE points only ----
    Frag8 afrag[4];
    if (pbits) {
        int kidx = l15 < KK ? l15 : 0;
        float kx = kpts[kidx * 3 + 0];
        float ky = kpts[kidx * 3 + 1];
        float kz = kpts[kidx * 3 + 2];
        if (l15 >= KK) { kx = 3e4f; ky = 3e4f; kz = 3e4f; }  // pad kp -> w = 0
#pragma unroll
        for (int i = 0; i < 4; ++i) {
            if (!(pbits & (1 << i))) continue;
            int p = wid * 4 + i;
            int n = n0 + p;
            int nc = n < N ? n : 0;
            float qkx = q_pts[nc * 3 + 0] + kx;   // s - (q+kp): err ~6e-8 << d
            float qky = q_pts[nc * 3 + 1] + ky;
            float qkz = q_pts[nc * 3 + 2] + kz;
            int base = p * 512 + q * 8;
            float4v x0 = *(float4v*)&fp[base],      x1 = *(float4v*)&fp[base + 4];
            float4v y0 = *(float4v*)&fp[base + 32], y1 = *(float4v*)&fp[base + 36];
            float4v z0 = *(float4v*)&fp[base + 64], z1 = *(float4v*)&fp[base + 68];
            float w[8];
#pragma unroll
            for (int j = 0; j < 8; ++j) {
                float dx = (j < 4 ? x0[j & 3] : x1[j & 3]) - qkx;
                float dy = (j < 4 ? y0[j & 3] : y1[j & 3]) - qky;
                float dz = (j < 4 ? z0[j & 3] : z1[j & 3]) - qkz;
                float d = __builtin_amdgcn_sqrtf(fmaf(dx, dx, fmaf(dy, dy, dz * dz)));
                w[j] = fmaxf(fmaf(d, -INV_EXT, 1.0f), 0.0f);
            }
#pragma unroll
            for (int jj = 0; jj < 4; ++jj)
                afrag[i].u[jj] = pk_bf16(w[2 * jj], w[2 * jj + 1]);
        }
    }

    // ---- phase 2: active points -> gather x + MFMA; inactive -> zero wtS row ----
#pragma unroll
    for (int i = 0; i < 4; ++i) {
        int p = wid * 4 + i;
        if (pbits & (1 << i)) {
            int ibase = p * HN + q * 8;
            int4v ia = *(int4v*)&indS[ibase];       // broadcast b128
            int4v ib = *(int4v*)&indS[ibase + 4];
            const float* rpf[8];
#pragma unroll
            for (int j = 0; j < 8; ++j) {
                int idx = j < 4 ? ia[j] : ib[j - 4];
                rpf[j] = x + (size_t)idx * CIN;
            }
#pragma unroll
            for (int ct = 0; ct < 4; ++ct) {
                short8 b;
#pragma unroll
                for (int j = 0; j < 8; ++j)
                    b[j] = (short)rh_bf16(rpf[j][ct * 16 + l15]);
                float4v acc = {0.f, 0.f, 0.f, 0.f};
                acc = __builtin_amdgcn_mfma_f32_16x16x32_bf16(afrag[i].s, b, acc, 0, 0, 0);
                // D row m = k' = q*4+r, col n = c = ct*16+l15.
                // kd-slot j = quad*4 + r, quad = l15 + 16*(q^ct) + 64*ct
                uint2v v2;
                v2[0] = pk_bf16(acc[0], acc[1]);
                v2[1] = pk_bf16(acc[2], acc[3]);
                int quad = l15 + 16 * (q ^ ct) + 64 * ct;
                *(uint2v*)&wtS[wtJ(p, quad * 4)] = v2;
            }
        } else {
            // zero the 2 KB row: 64 lanes x 32 B (swizzle-agnostic: zeros)
            uint4v z = {0u, 0u, 0u, 0u};
            *(uint4v*)&wtS[p * KDIM + lane * 16]     = z;
            *(uint4v*)&wtS[p * KDIM + lane * 16 + 8] = z;
        }
    }
    __syncthreads();

    // ---- phase 3: OUT[16p x 64d] = wt[16p x 1024j] @ W3[1024j x 64d] ----
    const int d0 = wid * 16;
    float4v acc3 = {0.f, 0.f, 0.f, 0.f};
    const ushort_t* wb = W3 + (size_t)q * 512 + (d0 + l15) * 8;
#pragma unroll 8
    for (int s = 0; s < 32; ++s) {
        short8 a = *(short8*)&wtS[wtJ(l15, s * 32 + q * 8)];
        short8 bb2 = *(const short8*)(wb + (size_t)s * 2048);
        acc3 = __builtin_amdgcn_mfma_f32_16x16x32_bf16(a, bb2, acc3, 0, 0, 0);
    }

    // ---- epilogue: store + stats for ACTIVE rows only ----
    {
        float s1 = 0.f, s2 = 0.f;
#pragma unroll
        for (int r = 0; r < 4; ++r) {
            int p = q * 4 + r;
            int n = n0 + p;
            float v = acc3[r];
            if (((ba >> p) & 1) && n < N) {
                out[n * COUT + d0 + l15] = v;
                s1 += v; s2 += v * v;
            }
        }
        s1 += __shfl_xor(s1, 16); s2 += __shfl_xor(s2, 16);
        s1 += __shfl_xor(s1, 32); s2 += __shfl_xor(s2, 32);
        if (q == 0) {
            int slot = blockIdx.x & (NSLOT - 1);
            atomicAdd(&sums[slot * 128 + d0 + l15], s1);
            atomicAdd(&sums[slot * 128 + 64 + d0 + l15], s2);
        }
    }
}

// ================= K0: prep (zero stats, W->W3 blocked layout) ================
__global__ void prep_kernel(const float* __restrict__ W, float* sums, ushort_t* W3)
{
    int gt = blockIdx.x * 256 + threadIdx.x;
    int stride = gridDim.x * 256;
    if (gt < NSLOT * 128) sums[gt] = 0.f;
    for (int i = gt; i < COUT * KDIM; i += stride) {
        int d = (i >> 3) & 63;
        int j = ((i >> 9) << 3) | (i & 7);  // kd-slot
        int quad = j >> 2, r = j & 3;
        int l15 = quad & 15, e = (quad >> 4) & 3, ct = quad >> 6;
        int k = (e ^ ct) * 4 + r, c = ct * 16 + l15;
        W3[i] = (k < KK) ? rh_bf16(W[(k * CIN + c) * COUT + d]) : (ushort_t)0;
    }
}

// ====== K2: reduce slots + instance-norm + LeakyReLU (mask-aware) =============
// Inactive rows (pre-norm value exactly 0, never written by main) get the
// per-channel constant leaky((0-mean)*inv) with NO read of out.
__global__ void norm_kernel(float* __restrict__ out, const float* __restrict__ sums,
                            const unsigned* __restrict__ mask, int N)
{
    __shared__ float meanS[64], invS[64], czS[64];
    int t = threadIdx.x;
    if (t < 64) {
        float s1 = 0.f, s2 = 0.f;
#pragma unroll
        for (int sl = 0; sl < NSLOT; ++sl) {
            s1 += sums[sl * 128 + t];
            s2 += sums[sl * 128 + 64 + t];
        }
        float invN = 1.0f / (float)N;
        float mean = s1 * invN;
        float var = fmaxf(s2 * invN - mean * mean, 0.f);
        float inv = rsqrtf(var + 1e-5f);
        meanS[t] = mean;
        invS[t] = inv;
        float cz = (0.f - mean) * inv;
        czS[t] = cz >= 0.f ? cz : 0.1f * cz;
    }
    __syncthreads();
    long total = (long)N * 16;   // float4 chunks
    for (long i = (long)blockIdx.x * blockDim.x + t; i < total;
         i += (long)gridDim.x * blockDim.x) {
        int cb = (int)((i * 4) & 63);
        long n = i >> 4;
        unsigned mw = mask[n >> 4];
        float4v v;
        if ((mw >> ((int)n & 15)) & 1) {
            v = *(float4v*)&out[i * 4];
#pragma unroll
            for (int j = 0; j < 4; ++j) {
                float val = (v[j] - meanS[cb + j]) * invS[cb + j];
                v[j] = val >= 0.f ? val : 0.1f * val;
            }
        } else {
#pragma unroll
            for (int j = 0; j < 4; ++j) v[j] = czS[cb + j];
        }
        *(float4v*)&out[i * 4] = v;
    }
}

extern "C" void kernel_launch(void* const* d_in, const int* in_sizes, int n_in,
                              void* d_out, int out_size, void* d_ws, size_t ws_size,
                              hipStream_t stream)
{
    const float* q  = (const float*)d_in[0];
    const float* s  = (const float*)d_in[1];
    const int* inds = (const int*)d_in[2];
    const float* x  = (const float*)d_in[3];
    const float* kp = (const float*)d_in[4];
    const float* W  = (const float*)d_in[5];
    float* out = (float*)d_out;
    int N = in_sizes[0] / 3;

    float* sums  = (float*)d_ws;                                  // 8 KB
    ushort_t* W3 = (ushort_t*)((char*)d_ws + 8192);               // 128 KB
    unsigned* mask = (unsigned*)((char*)d_ws + 8192 + 131072);    // nblk * 4 B

    int nblk = (N + PB - 1) / PB;
    prep_kernel<<<256, 256, 0, stream>>>(W, sums, W3);
    kpconv_main<<<nblk, 256, 0, stream>>>(q, s, inds, x, kp, W3, out, sums, mask, N);
    norm_kernel<<<2048, 256, 0, stream>>>(out, sums, mask, N);
}